// Round 4
// baseline (506.031 us; speedup 1.0000x reference)
//
#include <hip/hip_runtime.h>
#include <math.h>

#define DIM 1024
#define ROWS 16384
#define SEQ 4096
#define MARGIN 0.006f
#define NBUCK 256
#define BLO (-3.0f)
#define BW (6.0f / 256.0f)

typedef __bf16 v8bf __attribute__((ext_vector_type(8)));
typedef float v4f __attribute__((ext_vector_type(4)));

__device__ __forceinline__ unsigned short f2bf(float f){
  unsigned u = __float_as_uint(f);
  u = u + 0x7FFFu + ((u >> 16) & 1u);   // RNE
  return (unsigned short)(u >> 16);
}
__device__ __forceinline__ float bf2f(unsigned short h){
  return __uint_as_float(((unsigned)h) << 16);
}
__device__ __forceinline__ unsigned short relu_bf(unsigned short h){
  return (h & 0x8000u) ? (unsigned short)0 : h;
}

// ---------------- fp32 -> bf16 convert (x) ----------------
__global__ __launch_bounds__(256) void cvt_k(const float* __restrict__ s,
                                             unsigned short* __restrict__ d, int n){
  int i = (blockIdx.x * 256 + threadIdx.x) * 4;
  if (i + 3 < n){
    float4 f = *(const float4*)(s + i);
    ushort4 o;
    o.x = f2bf(f.x); o.y = f2bf(f.y); o.z = f2bf(f.z); o.w = f2bf(f.w);
    *(ushort4*)(d + i) = o;
  }
}

// ---------------- 5 weights -> one stacked bf16 buffer ----------------
__global__ __launch_bounds__(256) void cvt_w(
    const float* __restrict__ w0, const float* __restrict__ w1,
    const float* __restrict__ w2, const float* __restrict__ w3,
    const float* __restrict__ w4, unsigned short* __restrict__ dst){
  const float* srcs[5] = {w0, w1, w2, w3, w4};
  const float* s = srcs[blockIdx.y];
  int i = (blockIdx.x * 256 + threadIdx.x) * 4;
  float4 f = *(const float4*)(s + i);
  ushort4 o;
  o.x = f2bf(f.x); o.y = f2bf(f.y); o.z = f2bf(f.z); o.w = f2bf(f.w);
  *(ushort4*)(dst + ((size_t)blockIdx.y << 20) + i) = o;
}

// ------- bf16 GEMM: A(MxK) @ B(NtotxK)^T, outputs split per 1024 columns -------
__global__ __launch_bounds__(256, 4) void gemm_bt(
    const unsigned short* __restrict__ A, const unsigned short* __restrict__ B,
    const float* __restrict__ bias0, const float* __restrict__ bias1,
    void* __restrict__ C0, void* __restrict__ C1, void* __restrict__ C2,
    int bf16mask)
{
  __shared__ unsigned short lA[128 * 32];
  __shared__ unsigned short lB[128 * 32];
  const int t = threadIdx.x;
  const int lane = t & 63, wave = t >> 6;
  const int m0 = blockIdx.y * 128, n0 = blockIdx.x * 128;
  const int wm = (wave >> 1) * 64, wn = (wave & 1) * 64;
  const int ar = lane & 15, aq = lane >> 4;

  v4f acc[4][4];
#pragma unroll
  for (int i = 0; i < 4; i++)
#pragma unroll
    for (int j = 0; j < 4; j++) acc[i][j] = v4f{0.f, 0.f, 0.f, 0.f};

  for (int k0 = 0; k0 < DIM; k0 += 32){
#pragma unroll
    for (int i = 0; i < 2; i++){
      int c = (wave * 2 + i) * 64 + lane;        // 512 16B chunks per tile
      int row = c >> 2, kq = c & 3;
      __builtin_amdgcn_global_load_lds(
        (const __attribute__((address_space(1))) void*)(A + (size_t)(m0 + row) * DIM + k0 + kq * 8),
        (__attribute__((address_space(3))) void*)(&lA[c * 8]), 16, 0, 0);
      __builtin_amdgcn_global_load_lds(
        (const __attribute__((address_space(1))) void*)(B + (size_t)(n0 + row) * DIM + k0 + kq * 8),
        (__attribute__((address_space(3))) void*)(&lB[c * 8]), 16, 0, 0);
    }
    __syncthreads();
    v8bf af[4], bf[4];
#pragma unroll
    for (int i = 0; i < 4; i++){
      af[i] = *(const v8bf*)&lA[(wm + i * 16 + ar) * 32 + aq * 8];
      bf[i] = *(const v8bf*)&lB[(wn + i * 16 + ar) * 32 + aq * 8];
    }
#pragma unroll
    for (int mi = 0; mi < 4; mi++)
#pragma unroll
      for (int ni = 0; ni < 4; ni++)
        acc[mi][ni] = __builtin_amdgcn_mfma_f32_16x16x32_bf16(af[mi], bf[ni], acc[mi][ni], 0, 0, 0);
    __syncthreads();
  }

  const int os = n0 >> 10;                       // 1024-aligned segment, block-uniform
  void* Cp = (os == 0) ? C0 : ((os == 1) ? C1 : C2);
  const float* bp = (os == 0) ? bias0 : ((os == 1) ? bias1 : nullptr);
  const bool half_out = ((bf16mask >> os) & 1) != 0;
#pragma unroll
  for (int mi = 0; mi < 4; mi++)
#pragma unroll
    for (int ni = 0; ni < 4; ni++){
      int col = (n0 + wn + ni * 16 + ar) & (DIM - 1);
      float bv = bp ? bp[col] : 0.f;
#pragma unroll
      for (int rr = 0; rr < 4; rr++){
        int rowg = m0 + wm + mi * 16 + aq * 4 + rr;
        float val = acc[mi][ni][rr] + bv;
        if (half_out) ((unsigned short*)Cp)[(size_t)rowg * DIM + col] = f2bf(val);
        else          ((float*)Cp)[(size_t)rowg * DIM + col] = val;
      }
    }
}

// ---------------- top-64 select: single linear-bucket histogram ----------------
__global__ __launch_bounds__(256) void select_k(
  const float* __restrict__ gate_pre, const unsigned short* __restrict__ mag_pre,
  const float* __restrict__ x, const float* __restrict__ gW, const float* __restrict__ gb,
  unsigned short* __restrict__ xg)
{
  __shared__ unsigned hist[4][NBUCK];
  __shared__ unsigned sc[2];        // 0:b* 1:namb
  __shared__ int wna[4];
  __shared__ int ambIdx[128];
  __shared__ float ambEx[128];
  __shared__ unsigned short row16[DIM];
  __shared__ unsigned short smag[DIM];
  __shared__ float sx[DIM];

  const int r = blockIdx.x;
  const int t = threadIdx.x;
  const int lane = t & 63, wave = t >> 6;

  // P0: load gate/mag/x rows (coalesced), init LDS
  float4 v4 = *(const float4*)(gate_pre + (size_t)r * DIM + 4 * t);
  ushort4 m4 = *(const ushort4*)(mag_pre + (size_t)r * DIM + 4 * t);
  float4 x4 = *(const float4*)(x        + (size_t)r * DIM + 4 * t);
  float v[4] = {v4.x, v4.y, v4.z, v4.w};
  unsigned short mg[4] = {m4.x, m4.y, m4.z, m4.w};
  *(ushort4*)&smag[4*t] = m4;
  sx[4*t] = x4.x; sx[4*t+1] = x4.y; sx[4*t+2] = x4.z; sx[4*t+3] = x4.w;
  { uint2 z; z.x = 0u; z.y = 0u; *(uint2*)&row16[4*t] = z; }
#pragma unroll
  for (int w = 0; w < 4; w++) hist[w][t] = 0u;
  if (t < 2) sc[t] = 0u;
  if (t < 4) wna[t] = 0;
  __syncthreads();

  // P1: linear-bucket histogram (values spread ~4/bin -> minimal atomic chains)
  const float scale = 1.0f / BW;
#pragma unroll
  for (int j = 0; j < 4; j++){
    int bi = (int)floorf((v[j] - BLO) * scale);
    bi = bi < 0 ? 0 : (bi > 255 ? 255 : bi);
    atomicAdd(&hist[wave][bi], 1u);
  }
  __syncthreads();

  // P2: wave0 suffix-scan from top to find threshold bucket b*
  if (wave == 0){
    unsigned c[4];
    unsigned run = 0;
#pragma unroll
    for (int j = 0; j < 4; j++){
      int b = 255 - 4*lane - j;
      run += hist[0][b] + hist[1][b] + hist[2][b] + hist[3][b];
      c[j] = run;
    }
    unsigned incl = run;
#pragma unroll
    for (int off = 1; off < 64; off <<= 1){
      unsigned nb = __shfl_up(incl, off);
      if (lane >= off) incl += nb;
    }
    unsigned excl = incl - run;
#pragma unroll
    for (int j = 0; j < 4; j++){
      unsigned cum = excl + c[j];
      unsigned prev = (j == 0) ? excl : excl + c[j-1];
      if (cum >= 64u && prev < 64u) sc[0] = (unsigned)(255 - 4*lane - j);
    }
  }
  __syncthreads();
  const unsigned b1 = sc[0];
  float loe = BLO + (float)b1 * BW;
  float lo = (b1 == 0u)   ? -3.4e38f : loe - MARGIN;
  float hi = (b1 == 255u) ?  3.4e38f : loe + BW + MARGIN;

  // P3: classify; count certain winners, collect ambiguous
  int cnt = 0;
#pragma unroll
  for (int j = 0; j < 4; j++){
    float vv = v[j];
    if (vv > hi) cnt++;
    else if (vv >= lo){
      unsigned p = atomicAdd(&sc[1], 1u);
      if (p < 128u) ambIdx[p] = 4*t + j;
    }
  }
#pragma unroll
  for (int m = 32; m; m >>= 1) cnt += __shfl_xor(cnt, m);
  if (lane == 0) wna[wave] = cnt;
  __syncthreads();
  int na = wna[0] + wna[1] + wna[2] + wna[3];
  int namb = (int)sc[1]; if (namb > 128) namb = 128;
  int s = 64 - na;

  // P4: fp32-exact recompute of ambiguous gate_pre (one wave per candidate)
  for (int i = wave; i < namb; i += 4){
    int d = ambIdx[i];
    const float* wr = gW + (size_t)d * DIM;
    float p = 0.f;
    for (int k = lane; k < DIM; k += 64) p = fmaf(sx[k], wr[k], p);
#pragma unroll
    for (int m = 32; m; m >>= 1) p += __shfl_xor(p, m);
    if (lane == 0) ambEx[i] = p + gb[d];
  }
  __syncthreads();

  // P5: rank ambiguous (tie-break lower index), winners scatter into row16
  for (int i = t; i < namb; i += 256){
    float e = ambEx[i]; int d = ambIdx[i];
    int rank = 0;
    for (int j = 0; j < namb; j++){
      float ej = ambEx[j]; int dj = ambIdx[j];
      if (ej > e || (ej == e && dj < d)) rank++;
    }
    if (rank < s)
      row16[d] = (e > 0.f) ? relu_bf(smag[d]) : (unsigned short)0;
  }
  __syncthreads();

  // P6: dense merge + coalesced store (certain winners from registers)
  ushort4 o;
  unsigned short* op = (unsigned short*)&o;
#pragma unroll
  for (int j = 0; j < 4; j++){
    if (v[j] > hi) op[j] = (v[j] > 0.f) ? relu_bf(mg[j]) : (unsigned short)0;
    else           op[j] = row16[4*t + j];
  }
  *(ushort4*)(xg + (size_t)r * DIM + 4 * t) = o;
}

// ------- epilogue: 4 rows/block, prev row + inverse-norms carried in registers -------
__global__ __launch_bounds__(256) void epilogue_k(
  const unsigned short* __restrict__ q_pre, const unsigned short* __restrict__ k_pre,
  const unsigned short* __restrict__ p_pre, float* __restrict__ out)
{
  const int r0 = blockIdx.x * 4;
  const int t = threadIdx.x;
  const int lane = t & 63, wave = t >> 6;
  __shared__ float red[16];

  // preamble: load prev row (clamped at 0; unused when r0 is a segment start)
  const int rp = (r0 == 0) ? 0 : r0 - 1;
  float vqp[4], vkp[4], vpp[4];
  {
    ushort4 uq = *(const ushort4*)(q_pre + (size_t)rp * DIM + 4*t);
    ushort4 uk = *(const ushort4*)(k_pre + (size_t)rp * DIM + 4*t);
    ushort4 up = *(const ushort4*)(p_pre + (size_t)rp * DIM + 4*t);
    vqp[0]=bf2f(uq.x); vqp[1]=bf2f(uq.y); vqp[2]=bf2f(uq.z); vqp[3]=bf2f(uq.w);
    vkp[0]=bf2f(uk.x); vkp[1]=bf2f(uk.y); vkp[2]=bf2f(uk.z); vkp[3]=bf2f(uk.w);
    vpp[0]=bf2f(up.x); vpp[1]=bf2f(up.y); vpp[2]=bf2f(up.z); vpp[3]=bf2f(up.w);
  }
  float aq = 0.f, ak = 0.f;
#pragma unroll
  for (int j = 0; j < 4; j++){ aq = fmaf(vqp[j], vqp[j], aq); ak = fmaf(vkp[j], vkp[j], ak); }
#pragma unroll
  for (int m = 32; m; m >>= 1){ aq += __shfl_xor(aq, m); ak += __shfl_xor(ak, m); }
  if (lane == 0){ red[wave] = aq; red[4 + wave] = ak; }
  __syncthreads();
  float rqp = 1.f / fmaxf(sqrtf(red[0] + red[1] + red[2] + red[3]), 1e-12f);
  float rkp = 1.f / fmaxf(sqrtf(red[4] + red[5] + red[6] + red[7]), 1e-12f);
  __syncthreads();

  for (int rr = 0; rr < 4; rr++){
    const int r = r0 + rr;
    float vqc[4], vkc[4], vpc[4];
    {
      ushort4 uq = *(const ushort4*)(q_pre + (size_t)r * DIM + 4*t);
      ushort4 uk = *(const ushort4*)(k_pre + (size_t)r * DIM + 4*t);
      ushort4 up = *(const ushort4*)(p_pre + (size_t)r * DIM + 4*t);
      vqc[0]=bf2f(uq.x); vqc[1]=bf2f(uq.y); vqc[2]=bf2f(uq.z); vqc[3]=bf2f(uq.w);
      vkc[0]=bf2f(uk.x); vkc[1]=bf2f(uk.y); vkc[2]=bf2f(uk.z); vkc[3]=bf2f(uk.w);
      vpc[0]=bf2f(up.x); vpc[1]=bf2f(up.y); vpc[2]=bf2f(up.z); vpc[3]=bf2f(up.w);
    }
    const bool seg = (r & (SEQ - 1)) == 0;
    float aqc = 0.f, akc = 0.f;
#pragma unroll
    for (int j = 0; j < 4; j++){ aqc = fmaf(vqc[j], vqc[j], aqc); akc = fmaf(vkc[j], vkc[j], akc); }
    float dsum = 0.f;
    if (!seg){
#pragma unroll
      for (int j = 0; j < 2; j++){
        float ax = vpp[2*j], ay = vpp[2*j+1], bx = vpc[2*j], by = vpc[2*j+1];
        float ia = 1.f / fmaxf(sqrtf(ax * ax + ay * ay), 1e-12f);
        float ib = 1.f / fmaxf(sqrtf(bx * bx + by * by), 1e-12f);
        ax *= ia; ay *= ia; bx *= ib; by *= ib;
        float cross = ax * by - ay * bx;
        float dot = fminf(fmaxf(ax * bx + ay * by, -1.f), 1.f);
        dsum += fabsf(atan2f(cross, dot)) * 0.3183098861837907f;
      }
    }
#pragma unroll
    for (int m = 32; m; m >>= 1){
      aqc += __shfl_xor(aqc, m); akc += __shfl_xor(akc, m); dsum += __shfl_xor(dsum, m);
    }
    if (lane == 0){ red[wave] = aqc; red[4 + wave] = akc; red[8 + wave] = dsum; }
    __syncthreads();
    float rqc = 1.f / fmaxf(sqrtf(red[0] + red[1] + red[2] + red[3]), 1e-12f);
    float rkc = 1.f / fmaxf(sqrtf(red[4] + red[5] + red[6] + red[7]), 1e-12f);
    if (!seg){
      float tw = 0.f;
#pragma unroll
      for (int j = 0; j < 4; j++){
        float m = (vqc[j] * rqc) * (vkp[j] * rkp) - (vqp[j] * rqp) * (vkc[j] * rkc);
        tw = fmaf(m, m, tw);
      }
#pragma unroll
      for (int m = 32; m; m >>= 1) tw += __shfl_xor(tw, m);
      if (lane == 0) red[12 + wave] = tw;
      __syncthreads();
      if (t == 0){
        float dtot = red[8] + red[9] + red[10] + red[11];
        float twt = red[12] + red[13] + red[14] + red[15];
        out[r] = 0.5f * tanhf(sqrtf(twt)) + 0.5f * (dtot * (1.f / 512.f));
      }
    } else {
      if (t == 0) out[r] = 0.f;
    }
    __syncthreads();
#pragma unroll
    for (int j = 0; j < 4; j++){ vqp[j] = vqc[j]; vkp[j] = vkc[j]; vpp[j] = vpc[j]; }
    rqp = rqc; rkp = rkc;
  }
}

extern "C" void kernel_launch(void* const* d_in, const int* in_sizes, int n_in,
                              void* d_out, int out_size, void* d_ws, size_t ws_size,
                              hipStream_t stream)
{
  const float* x       = (const float*)d_in[0];
  const float* gate_W  = (const float*)d_in[1];
  const float* gate_b  = (const float*)d_in[2];
  const float* mag_W   = (const float*)d_in[3];
  const float* mag_b   = (const float*)d_in[4];
  const float* Wq      = (const float*)d_in[5];
  const float* Wk      = (const float*)d_in[6];
  const float* phase_W = (const float*)d_in[7];
  float* out = (float*)d_out;

  char* ws = (char*)d_ws;
  unsigned short* xbf = (unsigned short*)ws;                  // 32 MB @0 (reused as xg)
  unsigned short* wbf = (unsigned short*)(ws + 33554432);     // 10 MB @32M: [gate;mag;q;k;phase]
  float*          gate_pre = (float*)(ws + 46137344);         // 64 MB @44M (reused as q_pre bf16)
  unsigned short* mag_pre  = (unsigned short*)(ws + 113246208); // 32 MB @108M (reused as k_pre)
  unsigned short* p_pre    = (unsigned short*)(ws + 146800640); // 32 MB @140M
  unsigned short* q_pre = (unsigned short*)gate_pre;
  unsigned short* k_pre = mag_pre;

  dim3 b256(256);
  cvt_k<<<16384, b256, 0, stream>>>(x, xbf, ROWS * DIM);
  cvt_w<<<dim3(1024, 5), b256, 0, stream>>>(gate_W, mag_W, Wq, Wk, phase_W, wbf);

  // gate+mag fused GEMM (N=2048): seg0 = gate fp32, seg1 = mag bf16
  gemm_bt<<<dim3(16, 128), b256, 0, stream>>>(xbf, wbf, gate_b, mag_b,
                                              gate_pre, mag_pre, nullptr, 0b010);

  unsigned short* xg = xbf;   // xbf no longer needed
  select_k<<<ROWS, b256, 0, stream>>>(gate_pre, mag_pre, x, gate_W, gate_b, xg);

  // q+k+phase fused GEMM (N=3072), all bf16 out
  gemm_bt<<<dim3(24, 128), b256, 0, stream>>>(xg, wbf + (2u << 20), nullptr, nullptr,
                                              q_pre, k_pre, p_pre, 0b111);

  epilogue_k<<<ROWS / 4, b256, 0, stream>>>(q_pre, k_pre, p_pre, out);
}

// Round 5
// 422.053 us; speedup vs baseline: 1.1990x; 1.1990x over previous
//
#include <hip/hip_runtime.h>
#include <math.h>

#define DIM 1024
#define ROWS 16384
#define SEQ 4096
#define MARGIN 0.006f
#define MAXC 24

typedef __bf16 v8bf __attribute__((ext_vector_type(8)));
typedef float v4f __attribute__((ext_vector_type(4)));

__device__ __forceinline__ unsigned short f2bf(float f){
  unsigned u = __float_as_uint(f);
  u = u + 0x7FFFu + ((u >> 16) & 1u);   // RNE
  return (unsigned short)(u >> 16);
}
__device__ __forceinline__ float bf2f(unsigned short h){
  return __uint_as_float(((unsigned)h) << 16);
}
__device__ __forceinline__ unsigned short relu_bf(unsigned short h){
  return (h & 0x8000u) ? (unsigned short)0 : h;
}
__device__ __forceinline__ void lds_fence(){
  __asm__ volatile("s_waitcnt lgkmcnt(0)" ::: "memory");
}

// ---------------- fp32 -> bf16 convert (x) ----------------
__global__ __launch_bounds__(256) void cvt_k(const float* __restrict__ s,
                                             unsigned short* __restrict__ d, int n){
  int i = (blockIdx.x * 256 + threadIdx.x) * 4;
  if (i + 3 < n){
    float4 f = *(const float4*)(s + i);
    ushort4 o;
    o.x = f2bf(f.x); o.y = f2bf(f.y); o.z = f2bf(f.z); o.w = f2bf(f.w);
    *(ushort4*)(d + i) = o;
  }
}

// ---------------- 5 weights -> one stacked bf16 buffer ----------------
__global__ __launch_bounds__(256) void cvt_w(
    const float* __restrict__ w0, const float* __restrict__ w1,
    const float* __restrict__ w2, const float* __restrict__ w3,
    const float* __restrict__ w4, unsigned short* __restrict__ dst){
  const float* srcs[5] = {w0, w1, w2, w3, w4};
  const float* s = srcs[blockIdx.y];
  int i = (blockIdx.x * 256 + threadIdx.x) * 4;
  float4 f = *(const float4*)(s + i);
  ushort4 o;
  o.x = f2bf(f.x); o.y = f2bf(f.y); o.z = f2bf(f.z); o.w = f2bf(f.w);
  *(ushort4*)(dst + ((size_t)blockIdx.y << 20) + i) = o;
}

// ------- bf16 GEMM: A(MxK) @ B(NtotxK)^T, outputs split per 1024 columns -------
__global__ __launch_bounds__(256, 4) void gemm_bt(
    const unsigned short* __restrict__ A, const unsigned short* __restrict__ B,
    const float* __restrict__ bias0, const float* __restrict__ bias1,
    void* __restrict__ C0, void* __restrict__ C1, void* __restrict__ C2,
    int bf16mask)
{
  __shared__ unsigned short lA[128 * 32];
  __shared__ unsigned short lB[128 * 32];
  const int t = threadIdx.x;
  const int lane = t & 63, wave = t >> 6;
  const int m0 = blockIdx.y * 128, n0 = blockIdx.x * 128;
  const int wm = (wave >> 1) * 64, wn = (wave & 1) * 64;
  const int ar = lane & 15, aq = lane >> 4;

  v4f acc[4][4];
#pragma unroll
  for (int i = 0; i < 4; i++)
#pragma unroll
    for (int j = 0; j < 4; j++) acc[i][j] = v4f{0.f, 0.f, 0.f, 0.f};

  for (int k0 = 0; k0 < DIM; k0 += 32){
#pragma unroll
    for (int i = 0; i < 2; i++){
      int c = (wave * 2 + i) * 64 + lane;        // 512 16B chunks per tile
      int row = c >> 2, kq = c & 3;
      __builtin_amdgcn_global_load_lds(
        (const __attribute__((address_space(1))) void*)(A + (size_t)(m0 + row) * DIM + k0 + kq * 8),
        (__attribute__((address_space(3))) void*)(&lA[c * 8]), 16, 0, 0);
      __builtin_amdgcn_global_load_lds(
        (const __attribute__((address_space(1))) void*)(B + (size_t)(n0 + row) * DIM + k0 + kq * 8),
        (__attribute__((address_space(3))) void*)(&lB[c * 8]), 16, 0, 0);
    }
    __syncthreads();
    v8bf af[4], bf[4];
#pragma unroll
    for (int i = 0; i < 4; i++){
      af[i] = *(const v8bf*)&lA[(wm + i * 16 + ar) * 32 + aq * 8];
      bf[i] = *(const v8bf*)&lB[(wn + i * 16 + ar) * 32 + aq * 8];
    }
#pragma unroll
    for (int mi = 0; mi < 4; mi++)
#pragma unroll
      for (int ni = 0; ni < 4; ni++)
        acc[mi][ni] = __builtin_amdgcn_mfma_f32_16x16x32_bf16(af[mi], bf[ni], acc[mi][ni], 0, 0, 0);
    __syncthreads();
  }

  const int os = n0 >> 10;                       // 1024-aligned segment, block-uniform
  void* Cp = (os == 0) ? C0 : ((os == 1) ? C1 : C2);
  const float* bp = (os == 0) ? bias0 : ((os == 1) ? bias1 : nullptr);
  const bool half_out = ((bf16mask >> os) & 1) != 0;
#pragma unroll
  for (int mi = 0; mi < 4; mi++)
#pragma unroll
    for (int ni = 0; ni < 4; ni++){
      int col = (n0 + wn + ni * 16 + ar) & (DIM - 1);
      float bv = bp ? bp[col] : 0.f;
#pragma unroll
      for (int rr = 0; rr < 4; rr++){
        int rowg = m0 + wm + mi * 16 + aq * 4 + rr;
        float val = acc[mi][ni][rr] + bv;
        if (half_out) ((unsigned short*)Cp)[(size_t)rowg * DIM + col] = f2bf(val);
        else          ((float*)Cp)[(size_t)rowg * DIM + col] = val;
      }
    }
}

// ---- top-64 select: one row per WAVE, zero __syncthreads, bisection threshold ----
// lane l owns elements d = c*256 + l*4 + j  (c,j in 0..3)
__global__ __launch_bounds__(256) void select_k(
  const float* __restrict__ gate_pre, const unsigned short* __restrict__ mag_pre,
  const float* __restrict__ x, const float* __restrict__ gW, const float* __restrict__ gb,
  unsigned short* __restrict__ xg)
{
  __shared__ int   s_cnt[4];
  __shared__ int   s_idx[4][MAXC];
  __shared__ float s_ex [4][MAXC];
  __shared__ int   s_res[4][MAXC];

  const int t = threadIdx.x;
  const int lane = t & 63, wave = t >> 6;
  const int r = blockIdx.x * 4 + wave;
  const size_t rb = (size_t)r * DIM;

  // load row into registers (coalesced float4/ushort4)
  float vg[16], vx[16];
  unsigned short mg[16];
#pragma unroll
  for (int c = 0; c < 4; c++){
    float4 g4 = *(const float4*)(gate_pre + rb + c * 256 + lane * 4);
    float4 x4 = *(const float4*)(x        + rb + c * 256 + lane * 4);
    ushort4 m4 = *(const ushort4*)(mag_pre + rb + c * 256 + lane * 4);
    vg[c*4+0]=g4.x; vg[c*4+1]=g4.y; vg[c*4+2]=g4.z; vg[c*4+3]=g4.w;
    vx[c*4+0]=x4.x; vx[c*4+1]=x4.y; vx[c*4+2]=x4.z; vx[c*4+3]=x4.w;
    mg[c*4+0]=m4.x; mg[c*4+1]=m4.y; mg[c*4+2]=m4.z; mg[c*4+3]=m4.w;
  }
  if (lane == 0) s_cnt[wave] = 0;

  // bisection: bracket 64th-largest; invariant c(lo)>=64>c(hi), c(T)=#{v>T}
  float lo = -8.f, hi = 8.f;
#pragma unroll
  for (int it = 0; it < 15; it++){
    float mid = 0.5f * (lo + hi);
    int cn = 0;
#pragma unroll
    for (int e = 0; e < 16; e++) cn += (vg[e] > mid) ? 1 : 0;
#pragma unroll
    for (int m = 32; m; m >>= 1) cn += __shfl_xor(cn, m);
    if (cn >= 64) lo = mid; else hi = mid;
  }
  const float cl = lo - MARGIN, ch = hi + MARGIN;

  // count certain winners (v > ch)
  int n1 = 0;
#pragma unroll
  for (int e = 0; e < 16; e++) n1 += (vg[e] > ch) ? 1 : 0;
#pragma unroll
  for (int m = 32; m; m >>= 1) n1 += __shfl_xor(n1, m);
  const int s = 64 - n1;

  // collect ambiguous candidates (cl <= v <= ch) into per-wave LDS list
  lds_fence();
#pragma unroll
  for (int e = 0; e < 16; e++){
    float vv = vg[e];
    if (vv >= cl && vv <= ch){
      int p = atomicAdd(&s_cnt[wave], 1);
      if (p < MAXC) s_idx[wave][p] = (e >> 2) * 256 + lane * 4 + (e & 3);
    }
  }
  lds_fence();
  int namb = s_cnt[wave]; if (namb > MAXC) namb = MAXC;

  // fp32-exact recompute for each candidate (whole wave, x in registers)
  for (int i = 0; i < namb; i++){
    int d = s_idx[wave][i];
    const float* wr = gW + (size_t)d * DIM;
    float p = 0.f;
#pragma unroll
    for (int c = 0; c < 4; c++){
      float4 w4 = *(const float4*)(wr + c * 256 + lane * 4);
      p = fmaf(vx[c*4+0], w4.x, p); p = fmaf(vx[c*4+1], w4.y, p);
      p = fmaf(vx[c*4+2], w4.z, p); p = fmaf(vx[c*4+3], w4.w, p);
    }
#pragma unroll
    for (int m = 32; m; m >>= 1) p += __shfl_xor(p, m);
    if (lane == 0) s_ex[wave][i] = p + gb[d];
  }
  lds_fence();

  // rank candidates (tie-break lower index); mark winners with positive gate
  if (lane < namb){
    float e = s_ex[wave][lane]; int d = s_idx[wave][lane];
    int rank = 0;
    for (int j = 0; j < namb; j++){
      float ej = s_ex[wave][j]; int dj = s_idx[wave][j];
      if (ej > e || (ej == e && dj < d)) rank++;
    }
    s_res[wave][lane] = (rank < s && e > 0.f) ? 1 : 0;
  }
  lds_fence();

  // assemble output: certain winners from registers, candidate overrides from LDS
  unsigned short o16[16];
#pragma unroll
  for (int e = 0; e < 16; e++)
    o16[e] = (vg[e] > ch) ? ((vg[e] > 0.f) ? relu_bf(mg[e]) : (unsigned short)0)
                          : (unsigned short)0;
  for (int i = 0; i < namb; i++){
    int d = s_idx[wave][i];
    int res = s_res[wave][i];
    if (((d >> 2) & 63) == lane){
      int e = (d >> 8) * 4 + (d & 3);
      o16[e] = res ? relu_bf(mg[e]) : (unsigned short)0;
    }
  }
#pragma unroll
  for (int c = 0; c < 4; c++){
    ushort4 o; o.x = o16[c*4+0]; o.y = o16[c*4+1]; o.z = o16[c*4+2]; o.w = o16[c*4+3];
    *(ushort4*)(xg + rb + c * 256 + lane * 4) = o;
  }
}

// ------- epilogue: 4 rows/block, prev row + inverse-norms carried in registers -------
__global__ __launch_bounds__(256) void epilogue_k(
  const unsigned short* __restrict__ q_pre, const unsigned short* __restrict__ k_pre,
  const unsigned short* __restrict__ p_pre, float* __restrict__ out)
{
  const int r0 = blockIdx.x * 4;
  const int t = threadIdx.x;
  const int lane = t & 63, wave = t >> 6;
  __shared__ float red[16];

  const int rp = (r0 == 0) ? 0 : r0 - 1;
  float vqp[4], vkp[4], vpp[4];
  {
    ushort4 uq = *(const ushort4*)(q_pre + (size_t)rp * DIM + 4*t);
    ushort4 uk = *(const ushort4*)(k_pre + (size_t)rp * DIM + 4*t);
    ushort4 up = *(const ushort4*)(p_pre + (size_t)rp * DIM + 4*t);
    vqp[0]=bf2f(uq.x); vqp[1]=bf2f(uq.y); vqp[2]=bf2f(uq.z); vqp[3]=bf2f(uq.w);
    vkp[0]=bf2f(uk.x); vkp[1]=bf2f(uk.y); vkp[2]=bf2f(uk.z); vkp[3]=bf2f(uk.w);
    vpp[0]=bf2f(up.x); vpp[1]=bf2f(up.y); vpp[2]=bf2f(up.z); vpp[3]=bf2f(up.w);
  }
  float aq = 0.f, ak = 0.f;
#pragma unroll
  for (int j = 0; j < 4; j++){ aq = fmaf(vqp[j], vqp[j], aq); ak = fmaf(vkp[j], vkp[j], ak); }
#pragma unroll
  for (int m = 32; m; m >>= 1){ aq += __shfl_xor(aq, m); ak += __shfl_xor(ak, m); }
  if (lane == 0){ red[wave] = aq; red[4 + wave] = ak; }
  __syncthreads();
  float rqp = 1.f / fmaxf(sqrtf(red[0] + red[1] + red[2] + red[3]), 1e-12f);
  float rkp = 1.f / fmaxf(sqrtf(red[4] + red[5] + red[6] + red[7]), 1e-12f);
  __syncthreads();

  for (int rr = 0; rr < 4; rr++){
    const int r = r0 + rr;
    float vqc[4], vkc[4], vpc[4];
    {
      ushort4 uq = *(const ushort4*)(q_pre + (size_t)r * DIM + 4*t);
      ushort4 uk = *(const ushort4*)(k_pre + (size_t)r * DIM + 4*t);
      ushort4 up = *(const ushort4*)(p_pre + (size_t)r * DIM + 4*t);
      vqc[0]=bf2f(uq.x); vqc[1]=bf2f(uq.y); vqc[2]=bf2f(uq.z); vqc[3]=bf2f(uq.w);
      vkc[0]=bf2f(uk.x); vkc[1]=bf2f(uk.y); vkc[2]=bf2f(uk.z); vkc[3]=bf2f(uk.w);
      vpc[0]=bf2f(up.x); vpc[1]=bf2f(up.y); vpc[2]=bf2f(up.z); vpc[3]=bf2f(up.w);
    }
    const bool seg = (r & (SEQ - 1)) == 0;
    float aqc = 0.f, akc = 0.f;
#pragma unroll
    for (int j = 0; j < 4; j++){ aqc = fmaf(vqc[j], vqc[j], aqc); akc = fmaf(vkc[j], vkc[j], akc); }
    float dsum = 0.f;
    if (!seg){
#pragma unroll
      for (int j = 0; j < 2; j++){
        float ax = vpp[2*j], ay = vpp[2*j+1], bx = vpc[2*j], by = vpc[2*j+1];
        float ia = 1.f / fmaxf(sqrtf(ax * ax + ay * ay), 1e-12f);
        float ib = 1.f / fmaxf(sqrtf(bx * bx + by * by), 1e-12f);
        ax *= ia; ay *= ia; bx *= ib; by *= ib;
        float cross = ax * by - ay * bx;
        float dot = fminf(fmaxf(ax * bx + ay * by, -1.f), 1.f);
        dsum += fabsf(atan2f(cross, dot)) * 0.3183098861837907f;
      }
    }
#pragma unroll
    for (int m = 32; m; m >>= 1){
      aqc += __shfl_xor(aqc, m); akc += __shfl_xor(akc, m); dsum += __shfl_xor(dsum, m);
    }
    if (lane == 0){ red[wave] = aqc; red[4 + wave] = akc; red[8 + wave] = dsum; }
    __syncthreads();
    float rqc = 1.f / fmaxf(sqrtf(red[0] + red[1] + red[2] + red[3]), 1e-12f);
    float rkc = 1.f / fmaxf(sqrtf(red[4] + red[5] + red[6] + red[7]), 1e-12f);
    if (!seg){
      float tw = 0.f;
#pragma unroll
      for (int j = 0; j < 4; j++){
        float m = (vqc[j] * rqc) * (vkp[j] * rkp) - (vqp[j] * rqp) * (vkc[j] * rkc);
        tw = fmaf(m, m, tw);
      }
#pragma unroll
      for (int m = 32; m; m >>= 1) tw += __shfl_xor(tw, m);
      if (lane == 0) red[12 + wave] = tw;
      __syncthreads();
      if (t == 0){
        float dtot = red[8] + red[9] + red[10] + red[11];
        float twt = red[12] + red[13] + red[14] + red[15];
        out[r] = 0.5f * tanhf(sqrtf(twt)) + 0.5f * (dtot * (1.f / 512.f));
      }
    } else {
      if (t == 0) out[r] = 0.f;
    }
    __syncthreads();
#pragma unroll
    for (int j = 0; j < 4; j++){ vqp[j] = vqc[j]; vkp[j] = vkc[j]; vpp[j] = vpc[j]; }
    rqp = rqc; rkp = rkc;
  }
}

extern "C" void kernel_launch(void* const* d_in, const int* in_sizes, int n_in,
                              void* d_out, int out_size, void* d_ws, size_t ws_size,
                              hipStream_t stream)
{
  const float* x       = (const float*)d_in[0];
  const float* gate_W  = (const float*)d_in[1];
  const float* gate_b  = (const float*)d_in[2];
  const float* mag_W   = (const float*)d_in[3];
  const float* mag_b   = (const float*)d_in[4];
  const float* Wq      = (const float*)d_in[5];
  const float* Wk      = (const float*)d_in[6];
  const float* phase_W = (const float*)d_in[7];
  float* out = (float*)d_out;

  char* ws = (char*)d_ws;
  unsigned short* xbf = (unsigned short*)ws;                  // 32 MB @0 (reused as xg)
  unsigned short* wbf = (unsigned short*)(ws + 33554432);     // 10 MB @32M: [gate;mag;q;k;phase]
  float*          gate_pre = (float*)(ws + 46137344);         // 64 MB @44M (reused as q_pre bf16)
  unsigned short* mag_pre  = (unsigned short*)(ws + 113246208); // 32 MB @108M (reused as k_pre)
  unsigned short* p_pre    = (unsigned short*)(ws + 146800640); // 32 MB @140M
  unsigned short* q_pre = (unsigned short*)gate_pre;
  unsigned short* k_pre = mag_pre;

  dim3 b256(256);
  cvt_k<<<16384, b256, 0, stream>>>(x, xbf, ROWS * DIM);
  cvt_w<<<dim3(1024, 5), b256, 0, stream>>>(gate_W, mag_W, Wq, Wk, phase_W, wbf);

  // gate+mag fused GEMM (N=2048): seg0 = gate fp32, seg1 = mag bf16
  gemm_bt<<<dim3(16, 128), b256, 0, stream>>>(xbf, wbf, gate_b, mag_b,
                                              gate_pre, mag_pre, nullptr, 0b010);

  unsigned short* xg = xbf;   // xbf no longer needed
  select_k<<<ROWS / 4, b256, 0, stream>>>(gate_pre, mag_pre, x, gate_W, gate_b, xg);

  // q+k+phase fused GEMM (N=3072), all bf16 out
  gemm_bt<<<dim3(24, 128), b256, 0, stream>>>(xg, wbf + (2u << 20), nullptr, nullptr,
                                              q_pre, k_pre, p_pre, 0b111);

  epilogue_k<<<ROWS / 4, b256, 0, stream>>>(q_pre, k_pre, p_pre, out);
}